// Round 1
// 1037.168 us; speedup vs baseline: 1.2383x; 1.2383x over previous
//
#include <hip/hip_runtime.h>
#include <stdint.h>

#define T_STEPS 512
#define BATCH   4096
#define DIN     64
#define HID     70
#define KDIM    160      // K-span of one layer's weight panel (5 k-steps of 32)
#define KS      5
#define RB      16       // batch rows per block -> 256 blocks (1/CU)
#define WAVES   12       // 0..5 layer1, 6..11 layer0 (3 waves/SIMD)
#define NTHR    (WAVES*64)
#define NTILES  18       // tiles per layer; tile = 16 gate-rows = 4 h x 4 gates
#define CH      3        // tiles (output chains) per wave: 6 waves x 3 = 18
#define ASP     232      // merged LDS panel row stride in shorts (464 B: 16B-aligned,
                         // 116 dwords = 20 mod 32 banks -> only 2-way (free) aliasing)

typedef __bf16 bf16x8 __attribute__((ext_vector_type(8)));
typedef float  f32x4  __attribute__((ext_vector_type(4)));
typedef unsigned short ushort_t;
typedef ushort_t us4 __attribute__((ext_vector_type(4)));

#define NLOG2E   (-1.44269504088896340736f)
#define TWOLOG2E ( 2.88539008177792681472f)

__device__ __forceinline__ ushort_t f2bf(float f) {
    uint32_t u = __float_as_uint(f);
    u += 0x7fffu + ((u >> 16) & 1u);   // round-to-nearest-even
    return (ushort_t)(u >> 16);
}
__device__ __forceinline__ float sigm(float x) {
    return __builtin_amdgcn_rcpf(1.0f + __expf(-x));
}

// Fused LSTM pointwise on PRESCALED gates a = {-log2e*gi, -log2e*gf, 2log2e*gg, -log2e*go}
//   u = exp2(a) gives e^{-gate} (or e^{2g});  i*g = (v-1)/((1+u0)(1+v));
//   f = 1/(1+u1);  c' = f*c + i*g;  h = o*tanh(c') = (w-1)/((1+u3)(1+w)), w = e^{2c'}.
// 5 exp2 + 3 rcp (was 5 exp + 5 rcp + 5 scale-muls). exp2 inputs clamped at 88
// (2^88=3.1e26: denominator products stay finite for all reachable magnitudes;
// when they do overflow, rcp(inf)=0 gives the correct saturated limit).
// Pad chains (zero weights+bias) compute exactly h=0, c=0 -> no lane guard needed.
__device__ __forceinline__ float cell(const f32x4 a, float& cc) {
    float u0 = __builtin_amdgcn_exp2f(a[0]);
    float u1 = __builtin_amdgcn_exp2f(a[1]);
    float v  = __builtin_amdgcn_exp2f(fminf(a[2], 88.0f));
    float u3 = __builtin_amdgcn_exp2f(a[3]);
    float ig = (v - 1.0f) * __builtin_amdgcn_rcpf((1.0f + u0) * (1.0f + v));
    float f_ = __builtin_amdgcn_rcpf(1.0f + u1);
    float cn = fmaf(f_, cc, ig);
    cc = cn;
    float w  = __builtin_amdgcn_exp2f(fminf(cn * TWOLOG2E, 88.0f));
    return (w - 1.0f) * __builtin_amdgcn_rcpf((1.0f + u3) * (1.0f + w));
}

// Weight panels in MFMA operand-A layout, [NTILES][16 rows][KDIM] bf16, prescaled.
// Tile t, row m: h = 4t + (m>>2), gate = m&3 (torch gate-row = gate*70 + h); zero if h>=70.
// k cols, layer0: k<64 -> Wih0[g][k]; 64<=k<134 -> Whh0[g][k-64]; else 0
//         layer1: k<70 -> Wih1[g][k]; 80<=k<150 -> Whh1[g][k-80]; else 0
//   (layer1's k=0 sits at col 64 of the merged LDS panel [x | h0 | h1])
// Scale: gates i,f,o by -log2e; gate g by +2*log2e. Biases likewise (kept f32).
__global__ void prep_kernel(const float* __restrict__ Wih0, const float* __restrict__ Whh0,
                            const float* __restrict__ bih0, const float* __restrict__ bhh0,
                            const float* __restrict__ Wih1, const float* __restrict__ Whh1,
                            const float* __restrict__ bih1, const float* __restrict__ bhh1,
                            ushort_t* __restrict__ W0p, ushort_t* __restrict__ W1p,
                            float* __restrict__ B0p, float* __restrict__ B1p) {
    int idx = blockIdx.x * 256 + threadIdx.x;
    const int n = NTILES * 16 * KDIM;   // 46080
    if (idx < n) {
        int row = idx / KDIM, k = idx - row * KDIM;
        int t = row >> 4, m = row & 15;
        int gate = m & 3, h = 4*t + (m >> 2);
        float sc = (gate == 2) ? TWOLOG2E : NLOG2E;
        float v0 = 0.f, v1 = 0.f;
        if (h < HID) {
            int g = gate * HID + h;
            if (k < 64)        v0 = Wih0[g*64 + k];
            else if (k < 134)  v0 = Whh0[g*HID + (k - 64)];
            if (k < 70)                   v1 = Wih1[g*HID + k];
            else if (k >= 80 && k < 150)  v1 = Whh1[g*HID + (k - 80)];
        }
        W0p[idx] = f2bf(sc * v0);
        W1p[idx] = f2bf(sc * v1);
    }
    if (idx < NTILES*16) {
        int t = idx >> 4, m = idx & 15;
        int gate = m & 3, h = 4*t + (m >> 2);
        float sc = (gate == 2) ? TWOLOG2E : NLOG2E;
        float s0 = 0.f, s1 = 0.f;
        if (h < HID) {
            int g = gate * HID + h;
            s0 = sc * (bih0[g] + bhh0[g]);
            s1 = sc * (bih1[g] + bhh1[g]);
        }
        B0p[idx] = s0; B1p[idx] = s1;
    }
}

__global__ __launch_bounds__(NTHR) void lstm_kernel(
    const float* __restrict__ x,              // [T][B][64] fp32
    const ushort_t* __restrict__ W0p, const ushort_t* __restrict__ W1p,
    const float* __restrict__ B0p, const float* __restrict__ B1p,
    const float* __restrict__ W1h, const float* __restrict__ b1h,
    const float* __restrict__ W2h, const float* __restrict__ b2h,
    float* __restrict__ out)
{
    // Merged activation panel, double-buffered. Row = batch row (0..15).
    // cols 0..63: x(p+1) | 64..133: h0(p) | 144..213: h1(p-1) | pads stay 0.
    // L0 reads k=0..159 (panel col 0+), L1 reads k=0..159 at panel col 64+.
    __shared__ alignas(16) ushort_t P[2][RB*ASP];
    __shared__ float h1f[RB*HID];
    __shared__ float mid[RB*50];

    const int tid  = threadIdx.x;
    const int wave = tid >> 6;
    const int lane = tid & 63;
    const int n15  = lane & 15;          // batch row (MFMA N / B-frag index)
    const int q    = lane >> 4;          // k-chunk for frags; h-offset in C-tile
    const int blk  = blockIdx.x;
    const bool isL0 = (wave >= 6);
    const int lw   = isL0 ? wave - 6 : wave;
    const int t0   = lw * CH;

    const ushort_t* __restrict__ Wp = isL0 ? W0p : W1p;
    const float*    __restrict__ Bp = isL0 ? B0p : B1p;

    // Register weights: operand A. Lane (q,n15) holds row n15 of each tile,
    // k = ks*32 + q*8 .. +7.  3 chains x 5 ks = 15 bf16x8 (30 VGPR).
    bf16x8 wA[CH][KS];
    f32x4  bias[CH];                     // MFMA C-init: rows 4q..4q+3 of tile
    int    col[CH];                      // h this lane produces, per chain
    #pragma unroll
    for (int c = 0; c < CH; c++) {
        const int rowb = ((t0 + c)*16 + n15)*KDIM + q*8;
        #pragma unroll
        for (int ks = 0; ks < KS; ks++)
            wA[c][ks] = *(const bf16x8*)(Wp + rowb + ks*32);
        bias[c] = *(const f32x4*)(Bp + (t0 + c)*16 + q*4);
        col[c]  = (t0 + c)*4 + q;        // up to 71; pad chains are exact-zero
    }
    const int kbase = (isL0 ? 0 : 64) + n15*ASP + q*8;   // B-frag base (shorts)

    // zero both panel buffers (h(-1)=0, pads stay zero forever)
    for (int i = tid; i < 2*RB*ASP; i += NTHR) (&P[0][0])[i] = 0;

    // x staging: threads 384..639 (L0 waves 6..9), one f32x4 each
    const int  xt   = tid - 384;
    const bool xl   = (xt >= 0) && (xt < 256);
    const int  xrow = xt >> 4;
    const int  xcol = (xt & 15) * 4;
    const float* xptr = x + ((size_t)blk*RB + xrow)*DIN + xcol;

    f32x4 x0v, x1v, xcur;
    if (xl) {
        x0v  = *(const f32x4*)(xptr);
        x1v  = *(const f32x4*)(xptr + (size_t)1*(BATCH*DIN));
        xcur = *(const f32x4*)(xptr + (size_t)2*(BATCH*DIN));
    }
    __syncthreads();                 // zeros visible
    if (xl) {
        us4 s0, s1;
        #pragma unroll
        for (int e = 0; e < 4; e++) { s0[e] = f2bf(x0v[e]); s1[e] = f2bf(x1v[e]); }
        *(us4*)(&P[1][xrow*ASP + xcol]) = s0;   // x(0) -> prologue panel
        *(us4*)(&P[0][xrow*ASP + xcol]) = s1;   // x(1) -> phase-0 panel
    }
    __syncthreads();

    float cc[CH] = {0.f, 0.f, 0.f};  // c0 (L0 waves) or c1 (L1 waves)

    // ---- prologue: L0 step 0 from P[1] = [x(0), h0(-1)=0] ----
    if (isL0) {
        bf16x8 b[KS];
        #pragma unroll
        for (int ks = 0; ks < KS; ks++)
            b[ks] = *(const bf16x8*)(&P[1][kbase + ks*32]);
        f32x4 acc[CH];
        #pragma unroll
        for (int c = 0; c < CH; c++) acc[c] = bias[c];
        #pragma unroll
        for (int ks = 0; ks < KS; ks++) {
            #pragma unroll
            for (int c = 0; c < CH; c++)
                acc[c] = __builtin_amdgcn_mfma_f32_16x16x32_bf16(wA[c][ks], b[ks], acc[c], 0,0,0);
        }
        #pragma unroll
        for (int c = 0; c < CH; c++) {
            float hv = cell(acc[c], cc[c]);
            P[0][n15*ASP + 64 + col[c]] = f2bf(hv);   // h0(0)
        }
    }
    __syncthreads();

    // ---- main loop: phase p computes L1 step p  and  L0 step p+1 ----
    for (int p = 0; p < T_STEPS; p++) {
        const int cur = p & 1, nxt = cur ^ 1;
        f32x4 xn;
        if (xl) {
            const int tn = (p+3 < T_STEPS) ? p+3 : T_STEPS-1;
            xn = *(const f32x4*)(xptr + (size_t)tn*(BATCH*DIN));
        }
        bf16x8 b[KS];
        #pragma unroll
        for (int ks = 0; ks < KS; ks++)
            b[ks] = *(const bf16x8*)(&P[cur][kbase + ks*32]);
        f32x4 acc[CH];
        #pragma unroll
        for (int c = 0; c < CH; c++) acc[c] = bias[c];
        #pragma unroll
        for (int ks = 0; ks < KS; ks++) {
            #pragma unroll
            for (int c = 0; c < CH; c++)
                acc[c] = __builtin_amdgcn_mfma_f32_16x16x32_bf16(wA[c][ks], b[ks], acc[c], 0,0,0);
        }
        if (xl) {   // store x(p+2) into next panel (loaded last phase; long since arrived)
            us4 s;
            #pragma unroll
            for (int e = 0; e < 4; e++) s[e] = f2bf(xcur[e]);
            *(us4*)(&P[nxt][xrow*ASP + xcol]) = s;
        }
        #pragma unroll
        for (int c = 0; c < CH; c++) {
            float hv = cell(acc[c], cc[c]);
            ushort_t hb = f2bf(hv);
            if (isL0) {
                P[nxt][n15*ASP + 64 + col[c]] = hb;          // h0(p+1)
            } else {
                P[nxt][n15*ASP + 144 + col[c]] = hb;         // h1(p)
                if (p == T_STEPS-1 && col[c] < HID) h1f[n15*HID + col[c]] = hv;
            }
        }
        if (xl) xcur = xn;
        __syncthreads();
    }

    // ---- head: out = sigmoid(W2 @ relu(W1 @ h1 + b1) + b2) ----
    for (int uu = tid; uu < RB*50; uu += NTHR) {
        const int r = uu / 50, j = uu - r*50;
        float s = b1h[j];
        const float* wgt = W1h + j*HID;
        const float* hh  = h1f + r*HID;
        #pragma unroll 7
        for (int k = 0; k < HID; k++) s += wgt[k]*hh[k];
        mid[uu] = fmaxf(s, 0.0f);
    }
    __syncthreads();
    if (tid < RB) {
        float s = b2h[0];
        const float* m = mid + tid*50;
        #pragma unroll 10
        for (int j = 0; j < 50; j++) s += W2h[j]*m[j];
        out[blk*RB + tid] = sigm(s);
    }
}

extern "C" void kernel_launch(void* const* d_in, const int* in_sizes, int n_in,
                              void* d_out, int out_size, void* d_ws, size_t ws_size,
                              hipStream_t stream) {
    (void)in_sizes; (void)n_in; (void)out_size; (void)ws_size;
    const float* x    = (const float*)d_in[0];
    const float* Wih0 = (const float*)d_in[2];
    const float* Whh0 = (const float*)d_in[3];
    const float* bih0 = (const float*)d_in[4];
    const float* bhh0 = (const float*)d_in[5];
    const float* Wih1 = (const float*)d_in[6];
    const float* Whh1 = (const float*)d_in[7];
    const float* bih1 = (const float*)d_in[8];
    const float* bhh1 = (const float*)d_in[9];
    const float* W1h  = (const float*)d_in[10];
    const float* b1h  = (const float*)d_in[11];
    const float* W2h  = (const float*)d_in[12];
    const float* b2h  = (const float*)d_in[13];

    char* ws = (char*)d_ws;
    ushort_t* W0p = (ushort_t*)ws;                    // 18*16*160*2 = 92160 B
    ushort_t* W1p = (ushort_t*)(ws + 92160);          // 92160 B
    float*    B0p = (float*)(ws + 184320);            // 288 f32
    float*    B1p = (float*)(ws + 185472);            // 288 f32

    prep_kernel<<<180, 256, 0, stream>>>(Wih0, Whh0, bih0, bhh0,
                                         Wih1, Whh1, bih1, bhh1,
                                         W0p, W1p, B0p, B1p);
    lstm_kernel<<<BATCH/RB, NTHR, 0, stream>>>(x, W0p, W1p, B0p, B1p,
                                               W1h, b1h, W2h, b2h, (float*)d_out);
}